// Round 20
// baseline (241.243 us; speedup 1.0000x reference)
//
#include <hip/hip_runtime.h>
#include <hip/hip_bf16.h>
#include <math.h>

#define Bn   8
#define Sn   512
#define HIDn 768
#define Hn   12
#define DHn  64
#define Tn   (Bn * Sn)   // 4096
#define NW   2304        // 3*768 W rows

// d_out float plane offsets (elements), return order:
// (context_layer, attention_scores, value_scores, query_scores, key_scores)
#define OFF_CTX   0ull
#define OFF_ATTN  3145728ull     // 8*512*768
#define OFF_VAL   28311552ull    // + 8*12*512*512
#define OFF_QRY   53477376ull
#define OFF_KEY   78643200ull

#define PLANE     9437184ull     // 3*4096*768 elements (one bf16 qkv plane)
#define LCAP      8190           // per-block LDS candidate capacity (~32KB)

typedef short  s8v     __attribute__((ext_vector_type(8)));
typedef unsigned short u8v __attribute__((ext_vector_type(8)));
typedef unsigned short u4v __attribute__((ext_vector_type(4)));
typedef float  f32x4   __attribute__((ext_vector_type(4)));

#define MFMA(a, b, c) __builtin_amdgcn_mfma_f32_16x16x32_bf16((a), (b), (c), 0, 0, 0)

__device__ __forceinline__ unsigned short f2bf(float f) {   // RNE f32 -> bf16 bits
    unsigned int u = __float_as_uint(f);
    u += 0x7fffu + ((u >> 16) & 1u);
    return (unsigned short)(u >> 16);
}
__device__ __forceinline__ float bf2f(unsigned short h) {
    return __uint_as_float(((unsigned int)h) << 16);
}
__device__ __forceinline__ unsigned short sgnbf(float x) {  // bf16 bits of sign(x)
    return x > 0.f ? (unsigned short)0x3F80 : (x < 0.f ? (unsigned short)0xBF80 : (unsigned short)0);
}
// nontemporal 16B store: output planes are write-once-never-read.
__device__ __forceinline__ void ntst4(float* p, float x, float y, float z, float w) {
    f32x4 v = {x, y, z, w};
    __builtin_nontemporal_store(v, (f32x4*)p);
}
// vSt position for V-sign of (within-batch pos s, within-head dim d)
__device__ __forceinline__ int vst_col(int s, int d) {
    return ((s >> 6) << 6) + (((((s >> 3) & 7) ^ (d & 7))) << 3) + (s & 7);
}

// ---------------------------------------------------------------------------
// P0: fp32 -> bf16 convert + PRE-SWIZZLE (k ^= (row&7)<<3, within each
// 64-element chunk). hid gets hi+lo; W gets hi only (dropped WL*hH term
// covered by the 6e-3 refine threshold).
// ---------------------------------------------------------------------------
__global__ __launch_bounds__(256) void prep_kernel(
    const float* __restrict__ hid,
    const float* __restrict__ Wq, const float* __restrict__ Wk, const float* __restrict__ Wv,
    unsigned short* __restrict__ hidH, unsigned short* __restrict__ hidL,
    unsigned short* __restrict__ WH)
{
    const int NCH_HID = Tn * (HIDn / 8);      // 393216 16B-chunks
    const int NCH_W   = NW * (HIDn / 8);      // 221184
    const int total   = NCH_HID + NCH_W;
    for (int c = blockIdx.x * 256 + threadIdx.x; c < total; c += gridDim.x * 256) {
        const float* src; unsigned short *dH, *dL; int row, kc; bool wantL;
        if (c < NCH_HID) {
            row = c / 96; kc = c % 96;
            src = hid + (size_t)row * HIDn + kc * 8;
            dH = hidH; dL = hidL; wantL = true;
        } else {
            int c2 = c - NCH_HID;
            row = c2 / 96; kc = c2 % 96;
            const int which = row / HIDn, jw = row % HIDn;
            const float* W = (which == 0) ? Wq : (which == 1) ? Wk : Wv;
            src = W + (size_t)jw * HIDn + kc * 8;
            dH = WH; dL = nullptr; wantL = false;
        }
        float4 a = *(const float4*)src;
        float4 b = *(const float4*)(src + 4);
        const float f[8] = {a.x, a.y, a.z, a.w, b.x, b.y, b.z, b.w};
        u8v hv, lv;
        #pragma unroll
        for (int i = 0; i < 8; ++i) {
            unsigned short h = f2bf(f[i]);
            hv[i] = h;
            lv[i] = f2bf(f[i] - bf2f(h));
        }
        const int ks = (kc * 8) ^ ((row & 7) << 3);   // swizzled element pos
        *(u8v*)(dH + (size_t)row * HIDn + ks) = hv;
        if (wantL) *(u8v*)(dL + (size_t)row * HIDn + ks) = lv;
    }
}

// P fragment from full 128x128 bf16 LDS buffer (256B rows), kkk in 0..3
__device__ __forceinline__ s8v fragP(const unsigned char* P, int row, int kkk, int kg) {
    int byte = (row * 256 + kkk * 64 + kg * 16) ^ ((row & 7) << 4);
    return *(const s8v*)(P + byte);
}
// DIRECT-GLOBAL fragment from a pre-swizzled plane (row stride HIDn bf16).
__device__ __forceinline__ s8v gfrag(const unsigned short* __restrict__ rowbase,
                                     int lr, int kk, int kg) {
    const int byte = (kk * 64 + kg * 16) ^ ((lr & 7) << 4);
    return *(const s8v*)((const unsigned char*)(rowbase + (size_t)lr * HIDn) + byte);
}
// same with a k-chunk byte offset (kbyte = 128*k64chunk; swizzle is chunk-local)
__device__ __forceinline__ s8v gfragk(const unsigned short* __restrict__ rowbase,
                                      int lr, int kbyte, int kk, int kg) {
    const int byte = kbyte + ((kk * 64 + kg * 16) ^ ((lr & 7) << 4));
    return *(const s8v*)((const unsigned char*)(rowbase + (size_t)lr * HIDn) + byte);
}
// DIRECT-GLOBAL V^T fragment from vSt (row stride Sn bf16), kkk in 0..3 over 128 t
__device__ __forceinline__ s8v gfrag_v(const unsigned short* __restrict__ rowbase,
                                       int lr, int kkk, int kg) {
    const int byte = (kkk * 64 + kg * 16) ^ ((lr & 7) << 4);
    return *(const s8v*)((const unsigned char*)(rowbase + (size_t)lr * Sn) + byte);
}

// ---------------------------------------------------------------------------
// K1: QKV projection, 2-term bf16 MFMA: WH*(hidH + hidL), fragments read
// DIRECTLY from the pre-swizzled L2-resident planes -> ZERO LDS staging and
// ZERO K-loop barriers (compiler software-pipelines the pure load+MFMA loop).
// LDS holds only the candidate list. which==2 scatters V-signs into vSt.
// Near-zero candidates (|v| < 6e-3) refined IN-BLOCK (fp64, 1 wave/candidate).
// ---------------------------------------------------------------------------
__global__ __launch_bounds__(256, 3) void proj_mfma(
    const unsigned short* __restrict__ hidH, const unsigned short* __restrict__ hidL,
    const unsigned short* __restrict__ WH,
    const float* __restrict__ hid,
    const float* __restrict__ Wq, const float* __restrict__ Wk, const float* __restrict__ Wv,
    const float* __restrict__ bq, const float* __restrict__ bk, const float* __restrict__ bv,
    unsigned short* __restrict__ qH, unsigned short* __restrict__ qS,
    unsigned short* __restrict__ vSt)
{
    __shared__ unsigned bc[2 + LCAP];     // [0]=count, [1..]=codes (~32KB)
    const int nb    = blockIdx.x;         // 0..17
    const int which = nb / 6;
    const int jw0   = (nb % 6) * 128;
    const int t0    = blockIdx.y * 128;
    const float* bias = (which == 0) ? bq : (which == 1) ? bk : bv;
    const float* Wsel = (which == 0) ? Wq : (which == 1) ? Wk : Wv;
    const int wrow0 = which * HIDn + jw0; // row in concatenated W planes (== 0 mod 8)

    const int tid  = threadIdx.x;
    const int lane = tid & 63;
    const int wv   = tid >> 6;
    const int wm   = wv >> 1, wn = wv & 1;    // wm: t-range, wn: jw-range
    const int r    = lane & 15, kg = lane >> 4;

    const unsigned short* Ah = hidH + (size_t)t0 * HIDn;
    const unsigned short* Al = hidL + (size_t)t0 * HIDn;
    const unsigned short* Wp = WH   + (size_t)wrow0 * HIDn;

    if (tid == 0) bc[0] = 0;

    f32x4 acc[4][4] = {};   // [m: hid/t frag][n: W/jw frag]
    for (int kb = 0; kb < HIDn / 64; ++kb) {
        const int kbyte = kb * 128;
        s8v wf[4][2];
        #pragma unroll
        for (int n = 0; n < 4; ++n)
            #pragma unroll
            for (int kk = 0; kk < 2; ++kk)
                wf[n][kk] = gfragk(Wp, wn * 64 + n * 16 + r, kbyte, kk, kg);
        #pragma unroll
        for (int m = 0; m < 4; ++m) {
            const int arow = wm * 64 + m * 16 + r;
            s8v hHf[2], hLf[2];
            #pragma unroll
            for (int kk = 0; kk < 2; ++kk) {
                hHf[kk] = gfragk(Ah, arow, kbyte, kk, kg);
                hLf[kk] = gfragk(Al, arow, kbyte, kk, kg);
            }
            #pragma unroll
            for (int n = 0; n < 4; ++n)
                #pragma unroll
                for (int kk = 0; kk < 2; ++kk) {
                    acc[m][n] = MFMA(wf[n][kk], hHf[kk], acc[m][n]);  // WH*hidH
                    acc[m][n] = MFMA(wf[n][kk], hLf[kk], acc[m][n]);  // WH*hidL
                }
        }
    }
    __syncthreads();   // bc[0] init visible before epilogue atomics

    // epilogue: per lane, t fixed (=...+r), 4 consecutive jw per frag (=kg*4+reg)
    const int hh = (jw0 + wn * 64) >> 6;          // head index (const per thread)
    #pragma unroll
    for (int m = 0; m < 4; ++m) {
        const int t = t0 + wm * 64 + m * 16 + r;  // global token
        const size_t rowbase = ((size_t)(which * Tn + t)) * (size_t)HIDn;
        const int tsw = (t & 7) << 3;
        const int bb = t >> 9, s = t & 511;       // batch, within-batch pos
        #pragma unroll
        for (int n = 0; n < 4; ++n) {
            const int jw = jw0 + wn * 64 + n * 16 + kg * 4;
            const float4 bs4 = *(const float4*)&bias[jw];
            const float bsa[4] = {bs4.x, bs4.y, bs4.z, bs4.w};
            u4v hv, sv;
            #pragma unroll
            for (int reg = 0; reg < 4; ++reg) {
                float v = acc[m][n][reg] + bsa[reg];
                if (fabsf(v) < 6e-3f) {
                    unsigned idx = atomicAdd(bc, 1u);          // LDS atomic (fast)
                    if (idx < LCAP)
                        bc[2 + idx] = ((unsigned)t << 10) | (unsigned)(jw + reg);
                    else {   // statistically never: refine inline (serial fp64)
                        double dd = (double)bsa[reg];
                        const float* ar = hid  + (size_t)t * HIDn;
                        const float* wr = Wsel + (size_t)(jw + reg) * HIDn;
                        for (int k2 = 0; k2 < HIDn; ++k2)
                            dd += (double)ar[k2] * (double)wr[k2];
                        v = (float)dd;
                    }
                }
                hv[reg] = f2bf(v);
                sv[reg] = sgnbf(v);
            }
            const size_t p = rowbase + (size_t)(jw ^ tsw);  // quad stays contiguous
            *(u4v*)(qH + p) = hv;
            *(u4v*)(qS + p) = sv;
            if (which == 2) {   // V-signs -> transposed vSt
                #pragma unroll
                for (int reg = 0; reg < 4; ++reg) {
                    const int d = (jw & 63) + reg;          // within-head dim
                    const size_t rg = (size_t)((bb * Hn + hh) * 64 + d);
                    vSt[rg * Sn + vst_col(s, d)] = sv[reg];
                }
            }
        }
    }

    // ---- in-block fp64 refinement: one wave per candidate ----
    // __syncthreads drains the epilogue's global stores (vmcnt(0) before
    // s_barrier), so re-writing the same locations below is ordered.
    __syncthreads();
    const unsigned nloc = min(bc[0], (unsigned)LCAP);
    for (unsigned c = wv; c < nloc; c += 4) {
        const unsigned code = bc[2 + c];
        const int jw = code & 1023;
        const int t  = (code >> 10) & (Tn - 1);
        const float* ar = hid  + (size_t)t  * HIDn;
        const float* wr = Wsel + (size_t)jw * HIDn;
        double d = 0.0;
        #pragma unroll
        for (int i = 0; i < HIDn / 64; ++i)
            d += (double)ar[lane + i * 64] * (double)wr[lane + i * 64];
        #pragma unroll
        for (int off = 32; off; off >>= 1)
            d += __shfl_down(d, off, 64);
        if (lane == 0) {
            const float v = (float)(d + (double)bias[jw]);
            const size_t base = ((size_t)(which * Tn + t)) * HIDn
                              + (size_t)(jw ^ ((t & 7) << 3));
            qH[base] = f2bf(v);
            qS[base] = sgnbf(v);
            if (which == 2) {
                const int bb = t >> 9, s = t & 511;
                const int hh2 = jw >> 6, dd = jw & 63;
                const size_t rg = (size_t)((bb * Hn + hh2) * 64 + dd);
                vSt[rg * Sn + vst_col(s, dd)] = sgnbf(v);
            }
        }
    }
}

// ---------------------------------------------------------------------------
// K2: MERGED final pass, 32KB LDS. blockIdx.z in 0..3:
//   z==0: fused binary attention + context, direct-global Q/K/V fragments;
//         LDS holds only the full 128x128 P buffer (2 barriers/tile).
//   z>0 : fp score plane z-1 via bf16x1 MFMA, direct-global, zero LDS/barriers.
// All output-plane stores NONTEMPORAL.
// ---------------------------------------------------------------------------
__global__ __launch_bounds__(256) void scores_attn(
    const unsigned short* __restrict__ qH, const unsigned short* __restrict__ qS,
    const unsigned short* __restrict__ vSt,
    const float* __restrict__ mask, float* __restrict__ out)
{
    __shared__ unsigned char sm[32768];   // z==0: full P tile (128x128 bf16)
    const int z  = blockIdx.z;
    const int bh = blockIdx.y;
    const int b = bh / Hn, h = bh % Hn;
    const int s0 = blockIdx.x << 7;
    const int tid  = threadIdx.x;
    const int lane = tid & 63;
    const int wv   = tid >> 6;
    const int wm   = wv >> 1, wn = wv & 1;
    const int r    = lane & 15, kg = lane >> 4;

    if (z > 0) {
        // ======= fp score plane (which = z-1), bf16x1, direct-global frags =======
        const int which = z - 1;
        const unsigned short* Arow = qH + ((size_t)(which * Tn + b * Sn + s0)) * HIDn + h * DHn;
        const unsigned short* Brow = qH + ((size_t)(which * Tn + b * Sn)) * HIDn + h * DHn;

        const size_t plane = (which == 0) ? OFF_QRY : (which == 1) ? OFF_KEY : OFF_VAL;
        float* o = out + plane + (size_t)bh * (size_t)(Sn * Sn);

        // A fragments: tile-invariant -> load ONCE (32 VGPRs)
        s8v sA[4][2];
        #pragma unroll
        for (int i = 0; i < 4; ++i)
            #pragma unroll
            for (int kk = 0; kk < 2; ++kk)
                sA[i][kk] = gfrag(Arow, wm * 64 + i * 16 + r, kk, kg);

        #pragma unroll
        for (int tt = 0; tt < 4; ++tt) {
            const unsigned short* Bt = Brow + ((size_t)(tt << 7)) * HIDn;
            s8v tH[4][2];
            #pragma unroll
            for (int j = 0; j < 4; ++j)
                #pragma unroll
                for (int kk = 0; kk < 2; ++kk)
                    tH[j][kk] = gfrag(Bt, wn * 64 + j * 16 + r, kk, kg);

            f32x4 acc[4][4] = {};   // [j: t frag][i: s frag]
            #pragma unroll
            for (int i = 0; i < 4; ++i)
                #pragma unroll
                for (int j = 0; j < 4; ++j)
                    #pragma unroll
                    for (int kk = 0; kk < 2; ++kk)
                        acc[j][i] = MFMA(tH[j][kk], sA[i][kk], acc[j][i]);
            #pragma unroll
            for (int i = 0; i < 4; ++i) {
                const int s = s0 + wm * 64 + i * 16 + r;
                float* orow = o + (size_t)s * Sn;
                #pragma unroll
                for (int j = 0; j < 4; ++j) {
                    const int t = (tt << 7) + wn * 64 + j * 16 + kg * 4;
                    ntst4(orow + t, acc[j][i][0] * 0.125f, acc[j][i][1] * 0.125f,
                                    acc[j][i][2] * 0.125f, acc[j][i][3] * 0.125f);
                }
            }
        }
    } else {
        // ======= fused binary attention + context, direct-global operands =======
        const unsigned short* Qrow = qS + ((size_t)(b * Sn + s0)) * HIDn + h * DHn;
        const unsigned short* Krow = qS + ((size_t)(Tn + b * Sn)) * HIDn + h * DHn;
        const unsigned short* Vrow = vSt + (size_t)(bh * DHn) * Sn;   // + t via gfrag_v

        f32x4 acc2[4][2] = {};                            // ctx accum [si][di]
        float* o = out + OFF_ATTN + (size_t)bh * (size_t)(Sn * Sn);

        for (int tt = 0; tt < 4; ++tt) {
            const int t0 = tt << 7;
            const unsigned short* Kt = Krow + (size_t)t0 * HIDn;
            const unsigned short* Vt = Vrow + t0;         // 128-elem col offset (256B)

            // ---- QK^T tile 128x128, K=64, direct-global frags ----
            f32x4 acc[4][4] = {};   // [j: t frag][i: s frag]
            s8v tF[4][2];
            #pragma unroll
            for (int j = 0; j < 4; ++j)
                #pragma unroll
                for (int kk = 0; kk < 2; ++kk)
                    tF[j][kk] = gfrag(Kt, wn * 64 + j * 16 + r, kk, kg);
            #pragma unroll
            for (int i = 0; i < 4; ++i) {
                s8v sF[2];
                #pragma unroll
                for (int kk = 0; kk < 2; ++kk)
                    sF[kk] = gfrag(Qrow, wm * 64 + i * 16 + r, kk, kg);
                #pragma unroll
                for (int j = 0; j < 4; ++j)
                    #pragma unroll
                    for (int kk = 0; kk < 2; ++kk)
                        acc[j][i] = MFMA(tF[j][kk], sF[kk], acc[j][i]);
            }

            // ---- store scores (NT), derive probs bf16 in-register ----
            u4v pq[4][4];   // [i][j]
            #pragma unroll
            for (int i = 0; i < 4; ++i) {
                const int s = s0 + wm * 64 + i * 16 + r;
                float* orow = o + (size_t)s * Sn;
                #pragma unroll
                for (int j = 0; j < 4; ++j) {
                    const int t = t0 + wn * 64 + j * 16 + kg * 4;
                    const float4 mk = *(const float4*)&mask[b * Sn + t];
                    float vx = acc[j][i][0] * 0.125f + mk.x;
                    float vy = acc[j][i][1] * 0.125f + mk.y;
                    float vz = acc[j][i][2] * 0.125f + mk.z;
                    float vw = acc[j][i][3] * 0.125f + mk.w;
                    ntst4(orow + t, vx, vy, vz, vw);
                    pq[i][j][0] = vx > 0.f ? (unsigned short)0x3F80 : (unsigned short)0;
                    pq[i][j][1] = vy > 0.f ? (unsigned short)0x3F80 : (unsigned short)0;
                    pq[i][j][2] = vz > 0.f ? (unsigned short)0x3F80 : (unsigned short)0;
                    pq[i][j][3] = vw > 0.f ? (unsigned short)0x3F80 : (unsigned short)0;
                }
            }

            // ---- P -> full 32KB LDS buffer (each wave its own quadrant) ----
            if (tt > 0) __syncthreads();      // PV(prev tile) done reading P
            #pragma unroll
            for (int i = 0; i < 4; ++i) {
                const int sl = wm * 64 + i * 16 + r;
                #pragma unroll
                for (int j = 0; j < 4; ++j) {
                    const int tl = wn * 128 + j * 32 + kg * 8;   // byte col (t*2)
                    const int byte = (sl * 256 + tl) ^ ((sl & 7) << 4);
                    *(u4v*)(sm + byte) = pq[i][j];
                }
            }
            __syncthreads();                  // full P visible

            // ---- PV: all 4 k-slots, V^T direct-global, P from LDS ----
            #pragma unroll
            for (int hf = 0; hf < 2; ++hf) {
                #pragma unroll
                for (int si = 0; si < 4; ++si) {
                    s8v pf[2];
                    #pragma unroll
                    for (int kk = 0; kk < 2; ++kk)
                        pf[kk] = fragP(sm, wm * 64 + si * 16 + r, hf * 2 + kk, kg);
                    #pragma unroll
                    for (int di = 0; di < 2; ++di)
                        #pragma unroll
                        for (int kk = 0; kk < 2; ++kk) {
                            s8v vf = gfrag_v(Vt, wn * 32 + di * 16 + r, hf * 2 + kk, kg);
                            acc2[si][di] = MFMA(vf, pf[kk], acc2[si][di]);
                        }
                }
            }
        }

        // ---- ctx store (NT): lane s=r fixed, 4 consecutive d -> float4 ----
        #pragma unroll
        for (int si = 0; si < 4; ++si) {
            const int s = s0 + wm * 64 + si * 16 + r;
            #pragma unroll
            for (int di = 0; di < 2; ++di) {
                const int d0 = wn * 32 + di * 16 + kg * 4;
                ntst4(out + OFF_CTX + (size_t)(b * Sn + s) * HIDn + h * DHn + d0,
                      acc2[si][di][0], acc2[si][di][1], acc2[si][di][2], acc2[si][di][3]);
            }
        }
    }
}

extern "C" void kernel_launch(void* const* d_in, const int* in_sizes, int n_in,
                              void* d_out, int out_size, void* d_ws, size_t ws_size,
                              hipStream_t stream)
{
    const float* hid  = (const float*)d_in[0];
    const float* mask = (const float*)d_in[1];
    const float* Wq   = (const float*)d_in[2];
    const float* bq   = (const float*)d_in[3];
    const float* Wk   = (const float*)d_in[4];
    const float* bk   = (const float*)d_in[5];
    const float* Wv   = (const float*)d_in[6];
    const float* bv   = (const float*)d_in[7];
    float* out = (float*)d_out;

    unsigned short* qH  = (unsigned short*)d_ws;             // 18.87 MB each
    unsigned short* qS  = qH + PLANE;
    unsigned short* vSt = qS + PLANE;                        // 6.3 MB

    // bf16 pre-swizzled staging planes for proj, scratch in d_out's QRY
    // plane (consumed by proj_mfma BEFORE the merged kernel launches).
    unsigned short* hidH = (unsigned short*)(out + OFF_QRY);
    unsigned short* hidL = hidH + (size_t)Tn * HIDn;
    unsigned short* WH   = hidL + (size_t)Tn * HIDn;

    dim3 blk(256);
    prep_kernel<<<dim3(2048),     blk, 0, stream>>>(hid, Wq, Wk, Wv, hidH, hidL, WH);
    proj_mfma  <<<dim3(18, 32),   blk, 0, stream>>>(hidH, hidL, WH,
                                                    hid, Wq, Wk, Wv, bq, bk, bv,
                                                    qH, qS, vSt);
    scores_attn<<<dim3(4, 96, 4), blk, 0, stream>>>(qH, qS, vSt, mask, out);
}

// Round 21
// 207.961 us; speedup vs baseline: 1.1600x; 1.1600x over previous
//
#include <hip/hip_runtime.h>
#include <hip/hip_bf16.h>
#include <math.h>

#define Bn   8
#define Sn   512
#define HIDn 768
#define Hn   12
#define DHn  64
#define Tn   (Bn * Sn)   // 4096
#define NW   2304        // 3*768 W rows

// d_out float plane offsets (elements), return order:
// (context_layer, attention_scores, value_scores, query_scores, key_scores)
#define OFF_CTX   0ull
#define OFF_ATTN  3145728ull     // 8*512*768
#define OFF_VAL   28311552ull    // + 8*12*512*512
#define OFF_QRY   53477376ull
#define OFF_KEY   78643200ull

#define PLANE     9437184ull     // 3*4096*768 elements (one bf16 qkv plane)
#define LCAP      12000          // per-block LDS candidate capacity (48KB buffer)

typedef short  s8v     __attribute__((ext_vector_type(8)));
typedef unsigned short u8v __attribute__((ext_vector_type(8)));
typedef unsigned short u4v __attribute__((ext_vector_type(4)));
typedef float  f32x4   __attribute__((ext_vector_type(4)));

typedef __attribute__((address_space(3))) unsigned int       lds_u32;
typedef __attribute__((address_space(1))) const unsigned int glb_u32;

#define MFMA(a, b, c) __builtin_amdgcn_mfma_f32_16x16x32_bf16((a), (b), (c), 0, 0, 0)

__device__ __forceinline__ unsigned short f2bf(float f) {   // RNE f32 -> bf16 bits
    unsigned int u = __float_as_uint(f);
    u += 0x7fffu + ((u >> 16) & 1u);
    return (unsigned short)(u >> 16);
}
__device__ __forceinline__ float bf2f(unsigned short h) {
    return __uint_as_float(((unsigned int)h) << 16);
}
__device__ __forceinline__ unsigned short sgnbf(float x) {  // bf16 bits of sign(x)
    return x > 0.f ? (unsigned short)0x3F80 : (x < 0.f ? (unsigned short)0xBF80 : (unsigned short)0);
}
// nontemporal 16B store: output planes are write-once-never-read.
__device__ __forceinline__ void ntst4(float* p, float x, float y, float z, float w) {
    f32x4 v = {x, y, z, w};
    __builtin_nontemporal_store(v, (f32x4*)p);
}
// vSt position for V-sign of (within-batch pos s, within-head dim d)
__device__ __forceinline__ int vst_col(int s, int d) {
    return ((s >> 6) << 6) + (((((s >> 3) & 7) ^ (d & 7))) << 3) + (s & 7);
}

// ---------------------------------------------------------------------------
// P0: fp32 -> bf16 convert + PRE-SWIZZLE (k ^= (row&7)<<3). hid gets hi+lo;
// W gets hi only (dropped WL*hH term covered by the 6e-3 refine threshold).
// ---------------------------------------------------------------------------
__global__ __launch_bounds__(256) void prep_kernel(
    const float* __restrict__ hid,
    const float* __restrict__ Wq, const float* __restrict__ Wk, const float* __restrict__ Wv,
    unsigned short* __restrict__ hidH, unsigned short* __restrict__ hidL,
    unsigned short* __restrict__ WH)
{
    const int NCH_HID = Tn * (HIDn / 8);      // 393216 16B-chunks
    const int NCH_W   = NW * (HIDn / 8);      // 221184
    const int total   = NCH_HID + NCH_W;
    for (int c = blockIdx.x * 256 + threadIdx.x; c < total; c += gridDim.x * 256) {
        const float* src; unsigned short *dH, *dL; int row, kc; bool wantL;
        if (c < NCH_HID) {
            row = c / 96; kc = c % 96;
            src = hid + (size_t)row * HIDn + kc * 8;
            dH = hidH; dL = hidL; wantL = true;
        } else {
            int c2 = c - NCH_HID;
            row = c2 / 96; kc = c2 % 96;
            const int which = row / HIDn, jw = row % HIDn;
            const float* W = (which == 0) ? Wq : (which == 1) ? Wk : Wv;
            src = W + (size_t)jw * HIDn + kc * 8;
            dH = WH; dL = nullptr; wantL = false;
        }
        float4 a = *(const float4*)src;
        float4 b = *(const float4*)(src + 4);
        const float f[8] = {a.x, a.y, a.z, a.w, b.x, b.y, b.z, b.w};
        u8v hv, lv;
        #pragma unroll
        for (int i = 0; i < 8; ++i) {
            unsigned short h = f2bf(f[i]);
            hv[i] = h;
            lv[i] = f2bf(f[i] - bf2f(h));
        }
        const int ks = (kc * 8) ^ ((row & 7) << 3);   // swizzled element pos
        *(u8v*)(dH + (size_t)row * HIDn + ks) = hv;
        if (wantL) *(u8v*)(dL + (size_t)row * HIDn + ks) = lv;
    }
}

// fragment: 8 contiguous bf16 at (row, k=kk*32+kg*8), XOR-swizzled LDS, 128B rows
__device__ __forceinline__ s8v frag(const unsigned char* P, int row, int kk, int kg) {
    int byte = (row * 128 + kk * 64 + kg * 16) ^ ((row & 7) << 4);
    return *(const s8v*)(P + byte);
}
// P fragment from full 128x128 bf16 LDS buffer (256B rows), kkk in 0..3
__device__ __forceinline__ s8v fragP(const unsigned char* P, int row, int kkk, int kg) {
    int byte = (row * 256 + kkk * 64 + kg * 16) ^ ((row & 7) << 4);
    return *(const s8v*)(P + byte);
}
// DIRECT-GLOBAL fragment from a pre-swizzled plane (row stride HIDn bf16).
__device__ __forceinline__ s8v gfrag(const unsigned short* __restrict__ rowbase,
                                     int lr, int kk, int kg) {
    const int byte = (kk * 64 + kg * 16) ^ ((lr & 7) << 4);
    return *(const s8v*)((const unsigned char*)(rowbase + (size_t)lr * HIDn) + byte);
}
// DIRECT-GLOBAL V^T fragment from vSt (row stride Sn bf16), kkk in 0..3 over 128 t
__device__ __forceinline__ s8v gfrag_v(const unsigned short* __restrict__ rowbase,
                                       int lr, int kkk, int kg) {
    const int byte = (kkk * 64 + kg * 16) ^ ((lr & 7) << 4);
    return *(const s8v*)((const unsigned char*)(rowbase + (size_t)lr * Sn) + byte);
}

// stage one 128x64 bf16 tile (16KB, 128B rows) from a pre-swizzled plane, stride HIDn
__device__ __forceinline__ void gload_tile(const unsigned short* __restrict__ srcbase,
                                           unsigned char* ldsbase, int wv, int lane) {
    #pragma unroll
    for (int i = 0; i < 4; ++i) {
        const int chunk = wv * 4 + i;
        const int off = chunk * 1024 + lane * 16;     // byte within 128x128B tile
        const int row = off >> 7, bir = off & 127;
        const unsigned short* g = srcbase + (size_t)row * HIDn + (bir >> 1);
        __builtin_amdgcn_global_load_lds((glb_u32*)g, (lds_u32*)(ldsbase + chunk * 1024),
                                         16, 0, 0);
    }
}

// ---------------------------------------------------------------------------
// K1: QKV projection, 2-term bf16 MFMA: WH*(hidH + hidL). 48KB LDS,
// 2 barriers/K-step. which==2 scatters V-signs into vSt.
// Near-zero candidates (|v| < 6e-3) are refined IN-BLOCK (fp64, one wave per
// candidate) after the epilogue -- each output element belongs to exactly one
// block, so no global candidate list / extra dispatch is needed.
// ---------------------------------------------------------------------------
__global__ __launch_bounds__(256, 3) void proj_mfma(
    const unsigned short* __restrict__ hidH, const unsigned short* __restrict__ hidL,
    const unsigned short* __restrict__ WH,
    const float* __restrict__ hid,
    const float* __restrict__ Wq, const float* __restrict__ Wk, const float* __restrict__ Wv,
    const float* __restrict__ bq, const float* __restrict__ bk, const float* __restrict__ bv,
    unsigned short* __restrict__ qH, unsigned short* __restrict__ qS,
    unsigned short* __restrict__ vSt)
{
    __shared__ unsigned char sm[49152];   // b0 hidH | b1 hidL | b2 WH; then cand list
    const int nb    = blockIdx.x;         // 0..17
    const int which = nb / 6;
    const int jw0   = (nb % 6) * 128;
    const int t0    = blockIdx.y * 128;
    const float* bias = (which == 0) ? bq : (which == 1) ? bk : bv;
    const float* Wsel = (which == 0) ? Wq : (which == 1) ? Wk : Wv;
    const int wrow0 = which * HIDn + jw0; // row in concatenated W planes

    const int tid  = threadIdx.x;
    const int lane = tid & 63;
    const int wv   = tid >> 6;
    const int wm   = wv >> 1, wn = wv & 1;    // wm: t-range, wn: jw-range
    const int r    = lane & 15, kg = lane >> 4;

    f32x4 acc[4][4] = {};   // [m: hid/t frag][n: W/jw frag]
    for (int kb = 0; kb < HIDn; kb += 64) {
        gload_tile(hidH + (size_t)t0 * HIDn + kb,    sm,         wv, lane);
        gload_tile(hidL + (size_t)t0 * HIDn + kb,    sm + 16384, wv, lane);
        gload_tile(WH   + (size_t)wrow0 * HIDn + kb, sm + 32768, wv, lane);
        __syncthreads();   // staging drained

        s8v wf[4][2];
        #pragma unroll
        for (int n = 0; n < 4; ++n)
            #pragma unroll
            for (int kk = 0; kk < 2; ++kk)
                wf[n][kk] = frag(sm + 32768, wn * 64 + n * 16 + r, kk, kg);
        #pragma unroll
        for (int m = 0; m < 4; ++m) {
            int arow = wm * 64 + m * 16 + r;
            s8v hHf[2], hLf[2];
            #pragma unroll
            for (int kk = 0; kk < 2; ++kk) {
                hHf[kk] = frag(sm,         arow, kk, kg);
                hLf[kk] = frag(sm + 16384, arow, kk, kg);
            }
            #pragma unroll
            for (int n = 0; n < 4; ++n)
                #pragma unroll
                for (int kk = 0; kk < 2; ++kk) {
                    acc[m][n] = MFMA(wf[n][kk], hHf[kk], acc[m][n]);  // WH*hidH
                    acc[m][n] = MFMA(wf[n][kk], hLf[kk], acc[m][n]);  // WH*hidL
                }
        }
        __syncthreads();   // protect buffers before next K-step staging
    }

    // K-loop done; sm is dead -> reuse as block-local candidate list.
    unsigned* bc = (unsigned*)sm;       // bc[0]=count, bc[1..]=codes
    if (tid == 0) bc[0] = 0;
    __syncthreads();

    // epilogue: per lane, t fixed (=...+r), 4 consecutive jw per frag (=kg*4+reg)
    const int hh = (jw0 + wn * 64) >> 6;          // head index (const per thread)
    #pragma unroll
    for (int m = 0; m < 4; ++m) {
        const int t = t0 + wm * 64 + m * 16 + r;  // global token
        const size_t rowbase = ((size_t)(which * Tn + t)) * (size_t)HIDn;
        const int tsw = (t & 7) << 3;
        const int bb = t >> 9, s = t & 511;       // batch, within-batch pos
        #pragma unroll
        for (int n = 0; n < 4; ++n) {
            const int jw = jw0 + wn * 64 + n * 16 + kg * 4;
            const float4 bs4 = *(const float4*)&bias[jw];
            const float bsa[4] = {bs4.x, bs4.y, bs4.z, bs4.w};
            u4v hv, sv;
            #pragma unroll
            for (int reg = 0; reg < 4; ++reg) {
                float v = acc[m][n][reg] + bsa[reg];
                if (fabsf(v) < 6e-3f) {
                    unsigned idx = atomicAdd(bc, 1u);          // LDS atomic (fast)
                    if (idx < LCAP)
                        bc[1 + idx] = ((unsigned)t << 10) | (unsigned)(jw + reg);
                    else {   // statistically never: refine inline (serial fp64)
                        double dd = (double)bsa[reg];
                        const float* ar = hid  + (size_t)t * HIDn;
                        const float* wr = Wsel + (size_t)(jw + reg) * HIDn;
                        for (int k2 = 0; k2 < HIDn; ++k2)
                            dd += (double)ar[k2] * (double)wr[k2];
                        v = (float)dd;
                    }
                }
                hv[reg] = f2bf(v);
                sv[reg] = sgnbf(v);
            }
            const size_t p = rowbase + (size_t)(jw ^ tsw);  // quad stays contiguous
            *(u4v*)(qH + p) = hv;
            *(u4v*)(qS + p) = sv;
            if (which == 2) {   // V-signs -> transposed vSt
                #pragma unroll
                for (int reg = 0; reg < 4; ++reg) {
                    const int d = (jw & 63) + reg;          // within-head dim
                    const size_t rg = (size_t)((bb * Hn + hh) * 64 + d);
                    vSt[rg * Sn + vst_col(s, d)] = sv[reg];
                }
            }
        }
    }

    // ---- in-block fp64 refinement: one wave per candidate ----
    // __syncthreads drains the epilogue's global stores (vmcnt(0) before
    // s_barrier), so re-writing the same locations below is ordered.
    __syncthreads();
    const unsigned nloc = min(bc[0], (unsigned)LCAP);
    for (unsigned c = wv; c < nloc; c += 4) {
        const unsigned code = bc[1 + c];
        const int jw = code & 1023;
        const int t  = (code >> 10) & (Tn - 1);
        const float* ar = hid  + (size_t)t  * HIDn;
        const float* wr = Wsel + (size_t)jw * HIDn;
        double d = 0.0;
        #pragma unroll
        for (int i = 0; i < HIDn / 64; ++i)
            d += (double)ar[lane + i * 64] * (double)wr[lane + i * 64];
        #pragma unroll
        for (int off = 32; off; off >>= 1)
            d += __shfl_down(d, off, 64);
        if (lane == 0) {
            const float v = (float)(d + (double)bias[jw]);
            const size_t base = ((size_t)(which * Tn + t)) * HIDn
                              + (size_t)(jw ^ ((t & 7) << 3));
            qH[base] = f2bf(v);
            qS[base] = sgnbf(v);
            if (which == 2) {
                const int bb = t >> 9, s = t & 511;
                const int hh2 = jw >> 6, dd = jw & 63;
                const size_t rg = (size_t)((bb * Hn + hh2) * 64 + dd);
                vSt[rg * Sn + vst_col(s, dd)] = sgnbf(v);
            }
        }
    }
}

// ---------------------------------------------------------------------------
// K2: MERGED final pass, 32KB LDS. blockIdx.z in 0..3:
//   z==0: fused binary attention + context, direct-global Q/K/V fragments;
//         LDS holds only the full 128x128 P buffer (2 barriers/tile).
//   z>0 : fp score plane z-1 via bf16x1 MFMA, direct-global, zero LDS/barriers.
// All output-plane stores NONTEMPORAL.
// ---------------------------------------------------------------------------
__global__ __launch_bounds__(256) void scores_attn(
    const unsigned short* __restrict__ qH, const unsigned short* __restrict__ qS,
    const unsigned short* __restrict__ vSt,
    const float* __restrict__ mask, float* __restrict__ out)
{
    __shared__ unsigned char sm[32768];   // z==0: full P tile (128x128 bf16)
    const int z  = blockIdx.z;
    const int bh = blockIdx.y;
    const int b = bh / Hn, h = bh % Hn;
    const int s0 = blockIdx.x << 7;
    const int tid  = threadIdx.x;
    const int lane = tid & 63;
    const int wv   = tid >> 6;
    const int wm   = wv >> 1, wn = wv & 1;
    const int r    = lane & 15, kg = lane >> 4;

    if (z > 0) {
        // ======= fp score plane (which = z-1), bf16x1, direct-global frags =======
        const int which = z - 1;
        const unsigned short* Arow = qH + ((size_t)(which * Tn + b * Sn + s0)) * HIDn + h * DHn;
        const unsigned short* Brow = qH + ((size_t)(which * Tn + b * Sn)) * HIDn + h * DHn;

        const size_t plane = (which == 0) ? OFF_QRY : (which == 1) ? OFF_KEY : OFF_VAL;
        float* o = out + plane + (size_t)bh * (size_t)(Sn * Sn);

        // A fragments: tile-invariant -> load ONCE (32 VGPRs)
        s8v sA[4][2];
        #pragma unroll
        for (int i = 0; i < 4; ++i)
            #pragma unroll
            for (int kk = 0; kk < 2; ++kk)
                sA[i][kk] = gfrag(Arow, wm * 64 + i * 16 + r, kk, kg);

        #pragma unroll
        for (int tt = 0; tt < 4; ++tt) {
            const unsigned short* Bt = Brow + ((size_t)(tt << 7)) * HIDn;
            s8v tH[4][2];
            #pragma unroll
            for (int j = 0; j < 4; ++j)
                #pragma unroll
                for (int kk = 0; kk < 2; ++kk)
                    tH[j][kk] = gfrag(Bt, wn * 64 + j * 16 + r, kk, kg);

            f32x4 acc[4][4] = {};   // [j: t frag][i: s frag]
            #pragma unroll
            for (int i = 0; i < 4; ++i)
                #pragma unroll
                for (int j = 0; j < 4; ++j)
                    #pragma unroll
                    for (int kk = 0; kk < 2; ++kk)
                        acc[j][i] = MFMA(tH[j][kk], sA[i][kk], acc[j][i]);
            #pragma unroll
            for (int i = 0; i < 4; ++i) {
                const int s = s0 + wm * 64 + i * 16 + r;
                float* orow = o + (size_t)s * Sn;
                #pragma unroll
                for (int j = 0; j < 4; ++j) {
                    const int t = (tt << 7) + wn * 64 + j * 16 + kg * 4;
                    ntst4(orow + t, acc[j][i][0] * 0.125f, acc[j][i][1] * 0.125f,
                                    acc[j][i][2] * 0.125f, acc[j][i][3] * 0.125f);
                }
            }
        }
    } else {
        // ======= fused binary attention + context, direct-global operands =======
        const unsigned short* Qrow = qS + ((size_t)(b * Sn + s0)) * HIDn + h * DHn;
        const unsigned short* Krow = qS + ((size_t)(Tn + b * Sn)) * HIDn + h * DHn;
        const unsigned short* Vrow = vSt + (size_t)(bh * DHn) * Sn;   // + t via gfrag_v

        f32x4 acc2[4][2] = {};                            // ctx accum [si][di]
        float* o = out + OFF_ATTN + (size_t)bh * (size_t)(Sn * Sn);

        for (int tt = 0; tt < 4; ++tt) {
            const int t0 = tt << 7;
            const unsigned short* Kt = Krow + (size_t)t0 * HIDn;
            const unsigned short* Vt = Vrow + t0;         // 128-elem col offset (256B)

            // ---- QK^T tile 128x128, K=64, direct-global frags ----
            f32x4 acc[4][4] = {};   // [j: t frag][i: s frag]
            s8v tF[4][2];
            #pragma unroll
            for (int j = 0; j < 4; ++j)
                #pragma unroll
                for (int kk = 0; kk < 2; ++kk)
                    tF[j][kk] = gfrag(Kt, wn * 64 + j * 16 + r, kk, kg);
            #pragma unroll
            for (int i = 0; i < 4; ++i) {
                s8v sF[2];
                #pragma unroll
                for (int kk = 0; kk < 2; ++kk)
                    sF[kk] = gfrag(Qrow, wm * 64 + i * 16 + r, kk, kg);
                #pragma unroll
                for (int j = 0; j < 4; ++j)
                    #pragma unroll
                    for (int kk = 0; kk < 2; ++kk)
                        acc[j][i] = MFMA(tF[j][kk], sF[kk], acc[j][i]);
            }

            // ---- store scores (NT), derive probs bf16 in-register ----
            u4v pq[4][4];   // [i][j]
            #pragma unroll
            for (int i = 0; i < 4; ++i) {
                const int s = s0 + wm * 64 + i * 16 + r;
                float* orow = o + (size_t)s * Sn;
                #pragma unroll
                for (int j = 0; j < 4; ++j) {
                    const int t = t0 + wn * 64 + j * 16 + kg * 4;
                    const float4 mk = *(const float4*)&mask[b * Sn + t];
                    float vx = acc[j][i][0] * 0.125f + mk.x;
                    float vy = acc[j][i][1] * 0.125f + mk.y;
                    float vz = acc[j][i][2] * 0.125f + mk.z;
                    float vw = acc[j][i][3] * 0.125f + mk.w;
                    ntst4(orow + t, vx, vy, vz, vw);
                    pq[i][j][0] = vx > 0.f ? (unsigned short)0x3F80 : (unsigned short)0;
                    pq[i][j][1] = vy > 0.f ? (unsigned short)0x3F80 : (unsigned short)0;
                    pq[i][j][2] = vz > 0.f ? (unsigned short)0x3F80 : (unsigned short)0;
                    pq[i][j][3] = vw > 0.f ? (unsigned short)0x3F80 : (unsigned short)0;
                }
            }

            // ---- P -> full 32KB LDS buffer (each wave its own quadrant) ----
            if (tt > 0) __syncthreads();      // PV(prev tile) done reading P
            #pragma unroll
            for (int i = 0; i < 4; ++i) {
                const int sl = wm * 64 + i * 16 + r;
                #pragma unroll
                for (int j = 0; j < 4; ++j) {
                    const int tl = wn * 128 + j * 32 + kg * 8;   // byte col (t*2)
                    const int byte = (sl * 256 + tl) ^ ((sl & 7) << 4);
                    *(u4v*)(sm + byte) = pq[i][j];
                }
            }
            __syncthreads();                  // full P visible

            // ---- PV: all 4 k-slots, V^T direct-global, P from LDS ----
            #pragma unroll
            for (int hf = 0; hf < 2; ++hf) {
                #pragma unroll
                for (int si = 0; si < 4; ++si) {
                    s8v pf[2];
                    #pragma unroll
                    for (int kk = 0; kk < 2; ++kk)
                        pf[kk] = fragP(sm, wm * 64 + si * 16 + r, hf * 2 + kk, kg);
                    #pragma unroll
                    for (int di = 0; di < 2; ++di)
                        #pragma unroll
                        for (int kk = 0; kk < 2; ++kk) {
                            s8v vf = gfrag_v(Vt, wn * 32 + di * 16 + r, hf * 2 + kk, kg);
                            acc2[si][di] = MFMA(vf, pf[kk], acc2[si][di]);
                        }
                }
            }
        }

        // ---- ctx store (NT): lane s=r fixed, 4 consecutive d -> float4 ----
        #pragma unroll
        for (int si = 0; si < 4; ++si) {
            const int s = s0 + wm * 64 + si * 16 + r;
            #pragma unroll
            for (int di = 0; di < 2; ++di) {
                const int d0 = wn * 32 + di * 16 + kg * 4;
                ntst4(out + OFF_CTX + (size_t)(b * Sn + s) * HIDn + h * DHn + d0,
                      acc2[si][di][0], acc2[si][di][1], acc2[si][di][2], acc2[si][di][3]);
            }
        }
    }
}

extern "C" void kernel_launch(void* const* d_in, const int* in_sizes, int n_in,
                              void* d_out, int out_size, void* d_ws, size_t ws_size,
                              hipStream_t stream)
{
    const float* hid  = (const float*)d_in[0];
    const float* mask = (const float*)d_in[1];
    const float* Wq   = (const float*)d_in[2];
    const float* bq   = (const float*)d_in[3];
    const float* Wk   = (const float*)d_in[4];
    const float* bk   = (const float*)d_in[5];
    const float* Wv   = (const float*)d_in[6];
    const float* bv   = (const float*)d_in[7];
    float* out = (float*)d_out;

    unsigned short* qH  = (unsigned short*)d_ws;             // 18.87 MB each
    unsigned short* qS  = qH + PLANE;
    unsigned short* vSt = qS + PLANE;                        // 6.3 MB

    // bf16 pre-swizzled staging planes for proj, scratch in d_out's QRY
    // plane (consumed by proj_mfma BEFORE the merged kernel launches).
    unsigned short* hidH = (unsigned short*)(out + OFF_QRY);
    unsigned short* hidL = hidH + (size_t)Tn * HIDn;
    unsigned short* WH   = hidL + (size_t)Tn * HIDn;

    dim3 blk(256);
    prep_kernel<<<dim3(2048),     blk, 0, stream>>>(hid, Wq, Wk, Wv, hidH, hidL, WH);
    proj_mfma  <<<dim3(18, 32),   blk, 0, stream>>>(hidH, hidL, WH,
                                                    hid, Wq, Wk, Wv, bq, bk, bv,
                                                    qH, qS, vSt);
    scores_attn<<<dim3(4, 96, 4), blk, 0, stream>>>(qH, qS, vSt, mask, out);
}